// Round 3
// baseline (1247.289 us; speedup 1.0000x reference)
//
#include <hip/hip_runtime.h>

#define NN    100000   // N_NODES
#define F     64       // feature dim (= hidden dim)
#define NBUCK 391      // ceil(NN/256) buckets of 256 nodes
#define TILE  8192     // edges per binpack workgroup

// ---------------------------------------------------------------------------
__global__ __launch_bounds__(256) void zero_int(int* p, int n) {
    int i = blockIdx.x * 256 + threadIdx.x;
    if (i < n) p[i] = 0;
}

// Per-WG LDS histogram of dst>>8, merged with one global atomic per bucket.
__global__ __launch_bounds__(256) void bucket_hist(const int* __restrict__ dst, int E,
                                                   int* __restrict__ bcnt) {
    __shared__ int h[NBUCK];
    for (int i = threadIdx.x; i < NBUCK; i += 256) h[i] = 0;
    __syncthreads();
    int stride = gridDim.x * 256;
    for (int e = blockIdx.x * 256 + threadIdx.x; e < E; e += stride)
        atomicAdd(&h[dst[e] >> 8], 1);
    __syncthreads();
    for (int i = threadIdx.x; i < NBUCK; i += 256)
        if (h[i]) atomicAdd(&bcnt[i], h[i]);
}

// Exclusive scan of 391 bucket counts (single WG); writes bbase + cursor init.
__global__ __launch_bounds__(512) void bucket_scan(const int* __restrict__ bcnt,
                                                   int* __restrict__ bbase,
                                                   int* __restrict__ cursor, int E) {
    __shared__ int s[512];
    int t = threadIdx.x;
    int v = (t < NBUCK) ? bcnt[t] : 0;
    s[t] = v;
    __syncthreads();
    for (int off = 1; off < 512; off <<= 1) {
        int u = (t >= off) ? s[t - off] : 0;
        __syncthreads();
        s[t] += u;
        __syncthreads();
    }
    if (t < NBUCK) {
        int ex = s[t] - v;
        bbase[t]  = ex;
        cursor[t] = ex;
    }
    if (t == 0) bbase[NBUCK] = E;
}

// ---------------------------------------------------------------------------
// Tile counting-sort into 391 coarse buckets with LDS staging + coalesced
// flush. packed edge = (src<<8) | (dst & 255)  (src<2^17, 256 nodes/bucket).
// ---------------------------------------------------------------------------
__global__ __launch_bounds__(1024) void binpack(const int* __restrict__ src,
                                                const int* __restrict__ dst, int E,
                                                int* __restrict__ cursor,
                                                unsigned* __restrict__ packed) {
    __shared__ int hist[NBUCK];
    __shared__ int lofs[NBUCK];
    __shared__ int gbase[NBUCK];
    __shared__ int lcur[NBUCK];
    __shared__ int ss[512];
    __shared__ unsigned stage[TILE];          // 32 KB
    __shared__ unsigned short sbuck[TILE];    // 16 KB
    int t  = threadIdx.x;
    int t0 = blockIdx.x * TILE;
    int n  = min(TILE, E - t0);

    for (int i = t; i < NBUCK; i += 1024) hist[i] = 0;
    __syncthreads();
    // phase 1: per-tile bucket counts
    for (int i = t; i < n; i += 1024) atomicAdd(&hist[dst[t0 + i] >> 8], 1);
    __syncthreads();
    // phase 2: exclusive scan of hist (512 lanes work, all hit barriers)
    int v = 0;
    if (t < 512) { v = (t < NBUCK) ? hist[t] : 0; ss[t] = v; }
    __syncthreads();
    for (int off = 1; off < 512; off <<= 1) {
        int u = 0;
        if (t < 512 && t >= off) u = ss[t - off];
        __syncthreads();
        if (t < 512) ss[t] += u;
        __syncthreads();
    }
    // phase 3: local offsets + global space reservation (1 atomic/bucket/tile)
    if (t < NBUCK) {
        int ex = ss[t] - v;
        lofs[t] = ex;
        lcur[t] = ex;
        int c = hist[t];
        gbase[t] = c ? atomicAdd(&cursor[t], c) : 0;
    }
    __syncthreads();
    // phase 4: place into LDS staging, locally bucket-sorted
    for (int i = t; i < n; i += 1024) {
        int d = dst[t0 + i];
        int b = d >> 8;
        int p = atomicAdd(&lcur[b], 1);
        stage[p] = ((unsigned)src[t0 + i] << 8) | (unsigned)(d & 255);
        sbuck[p] = (unsigned short)b;
    }
    __syncthreads();
    // phase 5: coalesced flush — consecutive i in a bucket run -> consecutive
    // global positions (runs avg ~21 words)
    for (int i = t; i < n; i += 1024) {
        int b = sbuck[i];
        packed[gbase[b] + (i - lofs[b])] = stage[i];
    }
}

// Per-bucket in-degree from packed edges (LDS counters, no global atomics);
// dis = rsqrt(deg + 1)  (+1 = self-loop).
__global__ __launch_bounds__(256) void deg_dis(const unsigned* __restrict__ packed,
                                               const int* __restrict__ bbase,
                                               float* __restrict__ dis) {
    __shared__ int h[256];
    int b = blockIdx.x;
    int nbase = b << 8;
    int nloc = min(256, NN - nbase);
    for (int i = threadIdx.x; i < 256; i += 256) h[i] = 0;
    __syncthreads();
    int beg = bbase[b], end = bbase[b + 1];
    for (int e = beg + threadIdx.x; e < end; e += 256)
        atomicAdd(&h[packed[e] & 255], 1);
    __syncthreads();
    for (int i = threadIdx.x; i < nloc; i += 256)
        dis[nbase + i] = rsqrtf((float)h[i] + 1.0f);
}

// ---------------------------------------------------------------------------
// A = (X @ W) * dis[row].  16 rows/block, 256 threads, 4 outputs/thread.
// ---------------------------------------------------------------------------
__global__ __launch_bounds__(256) void gemm_scale(const float* __restrict__ X,
                                                  const float* __restrict__ W,
                                                  const float* __restrict__ dis,
                                                  float* __restrict__ A) {
    __shared__ float wl[64][64];
    __shared__ float xl[16][64];
    int tid = threadIdx.x;
    for (int t = tid; t < 64 * 64; t += 256) wl[t >> 6][t & 63] = W[t];
    size_t base = (size_t)blockIdx.x * 16 * F;
    for (int t = tid; t < 16 * 64; t += 256) xl[t >> 6][t & 63] = X[base + t];
    __syncthreads();

    int col = tid & 63;
    int w   = tid >> 6;
    float a0 = 0.f, a1 = 0.f, a2 = 0.f, a3 = 0.f;
#pragma unroll
    for (int k = 0; k < 64; ++k) {
        float wk = wl[k][col];
        a0 = fmaf(xl[w * 4 + 0][k], wk, a0);
        a1 = fmaf(xl[w * 4 + 1][k], wk, a1);
        a2 = fmaf(xl[w * 4 + 2][k], wk, a2);
        a3 = fmaf(xl[w * 4 + 3][k], wk, a3);
    }
    int row = blockIdx.x * 16 + w * 4;
    float acc[4] = {a0, a1, a2, a3};
#pragma unroll
    for (int q = 0; q < 4; ++q)
        A[(size_t)(row + q) * F + col] = acc[q] * dis[row + q];
}

// ---------------------------------------------------------------------------
// Aggregation: WG per bucket, LDS acc[256][64] seeded with self-loop rows.
// One wave per edge (lane = feature): coalesced 256 B gather + ds_add_f32
// (2-way bank alias = free). Fused epilogue: out = (relu?)(b + dis*acc).
// ---------------------------------------------------------------------------
__global__ __launch_bounds__(1024) void agg_lds(const float* __restrict__ A,
                                                const unsigned* __restrict__ packed,
                                                const int* __restrict__ bbase,
                                                const float* __restrict__ dis,
                                                const float* __restrict__ bias,
                                                float* __restrict__ out,
                                                int do_relu) {
    __shared__ float acc[256 * 64];   // 64 KB -> 2 WGs/CU, all 391 co-resident
    int b = blockIdx.x;
    int nbase = b << 8;
    int nloc = min(256, NN - nbase);
    int lane = threadIdx.x & 63;
    int wid  = threadIdx.x >> 6;      // 16 waves
    for (int i = threadIdx.x; i < nloc * 64; i += 1024)
        acc[i] = A[(size_t)nbase * 64 + i];      // self-loop seed
    __syncthreads();
    int beg = bbase[b], end = bbase[b + 1];
    int e = beg + wid;
    for (; e + 48 < end; e += 64) {   // 4-deep pipeline: 4 gathers in flight
        unsigned p0 = packed[e];
        unsigned p1 = packed[e + 16];
        unsigned p2 = packed[e + 32];
        unsigned p3 = packed[e + 48];
        float v0 = A[(size_t)(p0 >> 8) * 64 + lane];
        float v1 = A[(size_t)(p1 >> 8) * 64 + lane];
        float v2 = A[(size_t)(p2 >> 8) * 64 + lane];
        float v3 = A[(size_t)(p3 >> 8) * 64 + lane];
        atomicAdd(&acc[(p0 & 255u) * 64 + lane], v0);
        atomicAdd(&acc[(p1 & 255u) * 64 + lane], v1);
        atomicAdd(&acc[(p2 & 255u) * 64 + lane], v2);
        atomicAdd(&acc[(p3 & 255u) * 64 + lane], v3);
    }
    for (; e < end; e += 16) {
        unsigned p = packed[e];
        float v = A[(size_t)(p >> 8) * 64 + lane];
        atomicAdd(&acc[(p & 255u) * 64 + lane], v);
    }
    __syncthreads();
    for (int i = threadIdx.x; i < nloc * 64; i += 1024) {
        float vv = fmaf(dis[nbase + (i >> 6)], acc[i], bias[i & 63]);
        if (do_relu) vv = fmaxf(vv, 0.f);
        out[(size_t)nbase * 64 + i] = vv;
    }
}

extern "C" void kernel_launch(void* const* d_in, const int* in_sizes, int n_in,
                              void* d_out, int out_size, void* d_ws, size_t ws_size,
                              hipStream_t stream) {
    const float* x  = (const float*)d_in[0];
    const int*   ei = (const int*)d_in[1];   // [2,E]: src = ei[0:E], dst = ei[E:2E]
    const float* W1 = (const float*)d_in[2];
    const float* b1 = (const float*)d_in[3];
    const float* W2 = (const float*)d_in[4];
    const float* b2 = (const float*)d_in[5];
    float* out = (float*)d_out;
    int E = in_sizes[1] / 2;
    const int* src = ei;
    const int* dst = ei + E;

    // workspace layout (int/float elements)
    int*      ws_i   = (int*)d_ws;
    int*      bcnt   = ws_i + 0;                 // [391]
    int*      bbase  = ws_i + 512;               // [392]
    int*      cursor = ws_i + 1024;              // [391]
    float*    dis    = (float*)ws_i + 2048;      // [100000]
    unsigned* packed = (unsigned*)ws_i + 102400; // [E]
    size_t    aoff   = 102400 + (((size_t)E + 511) & ~(size_t)511);
    float*    A      = (float*)ws_i + aoff;      // [NN*64], 256 B aligned

    // ---- edge preprocessing (once; shared by both layers) ----
    zero_int<<<(NBUCK + 255) / 256, 256, 0, stream>>>(bcnt, NBUCK);
    bucket_hist<<<512, 256, 0, stream>>>(dst, E, bcnt);
    bucket_scan<<<1, 512, 0, stream>>>(bcnt, bbase, cursor, E);
    binpack<<<(E + TILE - 1) / TILE, 1024, 0, stream>>>(src, dst, E, cursor, packed);
    deg_dis<<<NBUCK, 256, 0, stream>>>(packed, bbase, dis);

    // ---- layer 1 ----
    gemm_scale<<<NN / 16, 256, 0, stream>>>(x, W1, dis, A);
    agg_lds<<<NBUCK, 1024, 0, stream>>>(A, packed, bbase, dis, b1, out, 1);
    // ---- layer 2 (reads h from d_out, overwrites d_out) ----
    gemm_scale<<<NN / 16, 256, 0, stream>>>(out, W2, dis, A);
    agg_lds<<<NBUCK, 1024, 0, stream>>>(A, packed, bbase, dis, b2, out, 0);
}

// Round 4
// 274.520 us; speedup vs baseline: 4.5435x; 4.5435x over previous
//
#include <hip/hip_runtime.h>

#define NN    100000   // N_NODES
#define F     64       // feature dim (= hidden dim)
#define NBUCK 391      // ceil(NN/256) buckets of 256 nodes
#define TILE  8192     // edges per binpack workgroup
#define CAP   6144     // node_sort LDS staging capacity (avg bucket ~3197, 16-sigma ~3650)

// ---------------------------------------------------------------------------
__global__ __launch_bounds__(256) void zero_int(int* p, int n) {
    int i = blockIdx.x * 256 + threadIdx.x;
    if (i < n) p[i] = 0;
}

// Per-WG LDS histogram of dst>>8, merged with one global atomic per bucket.
__global__ __launch_bounds__(256) void bucket_hist(const int* __restrict__ dst, int E,
                                                   int* __restrict__ bcnt) {
    __shared__ int h[NBUCK];
    for (int i = threadIdx.x; i < NBUCK; i += 256) h[i] = 0;
    __syncthreads();
    int stride = gridDim.x * 256;
    for (int e = blockIdx.x * 256 + threadIdx.x; e < E; e += stride)
        atomicAdd(&h[dst[e] >> 8], 1);
    __syncthreads();
    for (int i = threadIdx.x; i < NBUCK; i += 256)
        if (h[i]) atomicAdd(&bcnt[i], h[i]);
}

// Exclusive scan of 391 bucket counts (single WG); writes bbase + cursor init.
__global__ __launch_bounds__(512) void bucket_scan(const int* __restrict__ bcnt,
                                                   int* __restrict__ bbase,
                                                   int* __restrict__ cursor, int E) {
    __shared__ int s[512];
    int t = threadIdx.x;
    int v = (t < NBUCK) ? bcnt[t] : 0;
    s[t] = v;
    __syncthreads();
    for (int off = 1; off < 512; off <<= 1) {
        int u = (t >= off) ? s[t - off] : 0;
        __syncthreads();
        s[t] += u;
        __syncthreads();
    }
    if (t < NBUCK) {
        int ex = s[t] - v;
        bbase[t]  = ex;
        cursor[t] = ex;
    }
    if (t == 0) bbase[NBUCK] = E;
}

// ---------------------------------------------------------------------------
// Tile counting-sort into 391 coarse buckets with LDS staging + coalesced
// flush. packed edge = (src<<8) | (dst & 255)  (src<2^17, 256 nodes/bucket).
// ---------------------------------------------------------------------------
__global__ __launch_bounds__(1024) void binpack(const int* __restrict__ src,
                                                const int* __restrict__ dst, int E,
                                                int* __restrict__ cursor,
                                                unsigned* __restrict__ packed) {
    __shared__ int hist[NBUCK];
    __shared__ int lofs[NBUCK];
    __shared__ int gbase[NBUCK];
    __shared__ int lcur[NBUCK];
    __shared__ int ss[512];
    __shared__ unsigned stage[TILE];          // 32 KB
    __shared__ unsigned short sbuck[TILE];    // 16 KB
    int t  = threadIdx.x;
    int t0 = blockIdx.x * TILE;
    int n  = min(TILE, E - t0);

    for (int i = t; i < NBUCK; i += 1024) hist[i] = 0;
    __syncthreads();
    for (int i = t; i < n; i += 1024) atomicAdd(&hist[dst[t0 + i] >> 8], 1);
    __syncthreads();
    int v = 0;
    if (t < 512) { v = (t < NBUCK) ? hist[t] : 0; ss[t] = v; }
    __syncthreads();
    for (int off = 1; off < 512; off <<= 1) {
        int u = 0;
        if (t < 512 && t >= off) u = ss[t - off];
        __syncthreads();
        if (t < 512) ss[t] += u;
        __syncthreads();
    }
    if (t < NBUCK) {
        int ex = ss[t] - v;
        lofs[t] = ex;
        lcur[t] = ex;
        int c = hist[t];
        gbase[t] = c ? atomicAdd(&cursor[t], c) : 0;
    }
    __syncthreads();
    for (int i = t; i < n; i += 1024) {
        int d = dst[t0 + i];
        int b = d >> 8;
        int p = atomicAdd(&lcur[b], 1);
        stage[p] = ((unsigned)src[t0 + i] << 8) | (unsigned)(d & 255);
        sbuck[p] = (unsigned short)b;
    }
    __syncthreads();
    // coalesced flush: consecutive i in a bucket run -> consecutive global slots
    for (int i = t; i < n; i += 1024) {
        int b = sbuck[i];
        packed[gbase[b] + (i - lofs[b])] = stage[i];
    }
}

// ---------------------------------------------------------------------------
// Per-bucket LDS counting sort to full node order: bucket-sorted `packed` ->
// node-sorted `srt` (plain src index), coalesced flush. Also emits row_ptr
// and dis = rsqrt(deg+1) (fused; replaces deg_dis + global scans).
// ---------------------------------------------------------------------------
__global__ __launch_bounds__(512) void node_sort(const unsigned* __restrict__ packed,
                                                 const int* __restrict__ bbase,
                                                 int* __restrict__ row_ptr,
                                                 int* __restrict__ srt,
                                                 float* __restrict__ dis, int E) {
    __shared__ int h[256];
    __shared__ int ex[256];
    __shared__ int lcur[256];
    __shared__ int stage[CAP];                // 24 KB
    int b = blockIdx.x, t = threadIdx.x;
    int nbase = b << 8;
    int nloc = min(256, NN - nbase);
    int beg = bbase[b], end = bbase[b + 1];
    int n = end - beg;

    if (t < 256) h[t] = 0;
    __syncthreads();
    for (int i = beg + t; i < end; i += 512)
        atomicAdd(&h[packed[i] & 255u], 1);
    __syncthreads();
    int v = 0;
    if (t < 256) { v = h[t]; ex[t] = v; }
    __syncthreads();
    for (int off = 1; off < 256; off <<= 1) {
        int u = 0;
        if (t < 256 && t >= off) u = ex[t - off];
        __syncthreads();
        if (t < 256) ex[t] += u;
        __syncthreads();
    }
    if (t < nloc) {
        int e0 = ex[t] - v;                   // exclusive scan
        row_ptr[nbase + t] = beg + e0;
        lcur[t] = e0;
        dis[nbase + t] = rsqrtf((float)v + 1.0f);   // +1 = self-loop
    }
    if (b == 0 && t == 0) row_ptr[NN] = E;
    __syncthreads();
    if (n <= CAP) {
        for (int i = beg + t; i < end; i += 512) {
            unsigned p = packed[i];
            int pos = atomicAdd(&lcur[p & 255u], 1);
            stage[pos] = (int)(p >> 8);
        }
        __syncthreads();
        for (int i = t; i < n; i += 512) srt[beg + i] = stage[i];
    } else {
        // safety fallback (statistically unreachable): direct scattered place
        for (int i = beg + t; i < end; i += 512) {
            unsigned p = packed[i];
            int pos = atomicAdd(&lcur[p & 255u], 1);
            srt[beg + pos] = (int)(p >> 8);
        }
    }
}

// ---------------------------------------------------------------------------
// A = (X @ W) * dis[row].  16 rows/block, 256 threads, 4 outputs/thread.
// ---------------------------------------------------------------------------
__global__ __launch_bounds__(256) void gemm_scale(const float* __restrict__ X,
                                                  const float* __restrict__ W,
                                                  const float* __restrict__ dis,
                                                  float* __restrict__ A) {
    __shared__ float wl[64][64];
    __shared__ float xl[16][64];
    int tid = threadIdx.x;
    for (int t = tid; t < 64 * 64; t += 256) wl[t >> 6][t & 63] = W[t];
    size_t base = (size_t)blockIdx.x * 16 * F;
    for (int t = tid; t < 16 * 64; t += 256) xl[t >> 6][t & 63] = X[base + t];
    __syncthreads();

    int col = tid & 63;
    int w   = tid >> 6;
    float a0 = 0.f, a1 = 0.f, a2 = 0.f, a3 = 0.f;
#pragma unroll
    for (int k = 0; k < 64; ++k) {
        float wk = wl[k][col];
        a0 = fmaf(xl[w * 4 + 0][k], wk, a0);
        a1 = fmaf(xl[w * 4 + 1][k], wk, a1);
        a2 = fmaf(xl[w * 4 + 2][k], wk, a2);
        a3 = fmaf(xl[w * 4 + 3][k], wk, a3);
    }
    int row = blockIdx.x * 16 + w * 4;
    float acc[4] = {a0, a1, a2, a3};
#pragma unroll
    for (int q = 0; q < 4; ++q)
        A[(size_t)(row + q) * F + col] = acc[q] * dis[row + q];
}

// ---------------------------------------------------------------------------
// Gather aggregation + fused finalize (round-2 proven structure, 4-wide ILP).
// 16 lanes per node (float4/lane), 16 nodes per 256-thread block, 6250 WGs.
// out[i] = (relu?)( b + dis[i] * (A[i] + sum_{e: dst=i} A[src[e]]) )
// ---------------------------------------------------------------------------
__global__ __launch_bounds__(256) void agg_kernel(const float4* __restrict__ A4,
                                                  const int* __restrict__ row_ptr,
                                                  const int* __restrict__ srt,
                                                  const float* __restrict__ dis,
                                                  const float* __restrict__ bias,
                                                  float4* __restrict__ out,
                                                  int do_relu) {
    int sub  = threadIdx.x & 15;
    int node = blockIdx.x * 16 + (threadIdx.x >> 4);
    int beg = row_ptr[node], end = row_ptr[node + 1];
    float4 acc = A4[(size_t)node * 16 + sub];       // self-loop
    int j = beg;
    for (; j + 4 <= end; j += 4) {                  // 4 gathers in flight
        int s0 = srt[j], s1 = srt[j + 1], s2 = srt[j + 2], s3 = srt[j + 3];
        float4 v0 = A4[(size_t)s0 * 16 + sub];
        float4 v1 = A4[(size_t)s1 * 16 + sub];
        float4 v2 = A4[(size_t)s2 * 16 + sub];
        float4 v3 = A4[(size_t)s3 * 16 + sub];
        acc.x += (v0.x + v1.x) + (v2.x + v3.x);
        acc.y += (v0.y + v1.y) + (v2.y + v3.y);
        acc.z += (v0.z + v1.z) + (v2.z + v3.z);
        acc.w += (v0.w + v1.w) + (v2.w + v3.w);
    }
    for (; j < end; ++j) {
        float4 v0 = A4[(size_t)srt[j] * 16 + sub];
        acc.x += v0.x; acc.y += v0.y; acc.z += v0.z; acc.w += v0.w;
    }
    float dv = dis[node];
    float4 bb = ((const float4*)bias)[sub];
    float4 o;
    o.x = fmaf(dv, acc.x, bb.x);
    o.y = fmaf(dv, acc.y, bb.y);
    o.z = fmaf(dv, acc.z, bb.z);
    o.w = fmaf(dv, acc.w, bb.w);
    if (do_relu) {
        o.x = fmaxf(o.x, 0.f); o.y = fmaxf(o.y, 0.f);
        o.z = fmaxf(o.z, 0.f); o.w = fmaxf(o.w, 0.f);
    }
    out[(size_t)node * 16 + sub] = o;
}

extern "C" void kernel_launch(void* const* d_in, const int* in_sizes, int n_in,
                              void* d_out, int out_size, void* d_ws, size_t ws_size,
                              hipStream_t stream) {
    const float* x  = (const float*)d_in[0];
    const int*   ei = (const int*)d_in[1];   // [2,E]: src = ei[0:E], dst = ei[E:2E]
    const float* W1 = (const float*)d_in[2];
    const float* b1 = (const float*)d_in[3];
    const float* W2 = (const float*)d_in[4];
    const float* b2 = (const float*)d_in[5];
    float* out = (float*)d_out;
    int E = in_sizes[1] / 2;
    const int* src = ei;
    const int* dst = ei + E;

    // workspace layout (4 B elements)
    int*      ws_i    = (int*)d_ws;
    int*      bcnt    = ws_i + 0;                   // [391]
    int*      bbase   = ws_i + 512;                 // [392]
    int*      cursor  = ws_i + 1024;                // [391]
    int*      row_ptr = ws_i + 2048;                // [100001]
    float*    dis     = (float*)(ws_i + 102400);    // [100000]
    int*      srt     = ws_i + 202752;              // [E]
    size_t    epad    = ((size_t)E + 511) & ~(size_t)511;
    unsigned* packed  = (unsigned*)(ws_i + 202752 + epad);  // [E]
    float*    A       = (float*)(ws_i + 202752 + 2 * epad); // [NN*64], 256 B aligned

    // ---- edge preprocessing (once; shared by both layers) ----
    zero_int<<<(NBUCK + 255) / 256, 256, 0, stream>>>(bcnt, NBUCK);
    bucket_hist<<<512, 256, 0, stream>>>(dst, E, bcnt);
    bucket_scan<<<1, 512, 0, stream>>>(bcnt, bbase, cursor, E);
    binpack<<<(E + TILE - 1) / TILE, 1024, 0, stream>>>(src, dst, E, cursor, packed);
    node_sort<<<NBUCK, 512, 0, stream>>>(packed, bbase, row_ptr, srt, dis, E);

    // ---- layer 1 ----
    gemm_scale<<<NN / 16, 256, 0, stream>>>(x, W1, dis, A);
    agg_kernel<<<NN / 16, 256, 0, stream>>>((const float4*)A, row_ptr, srt, dis, b1,
                                            (float4*)out, 1);
    // ---- layer 2 (reads h from d_out, overwrites d_out) ----
    gemm_scale<<<NN / 16, 256, 0, stream>>>(out, W2, dis, A);
    agg_kernel<<<NN / 16, 256, 0, stream>>>((const float4*)A, row_ptr, srt, dis, b2,
                                            (float4*)out, 0);
}